// Round 5
// baseline (105.736 us; speedup 1.0000x reference)
//
#include <hip/hip_runtime.h>
#include <hip/hip_bf16.h>

// Problem sizes (fixed by the reference)
#define S_LEN 256     // sequence length (t)
#define DM    512     // d_model (k / d)
#define DR    512     // d_rnn (s)
#define NC    8       // t-chunks
#define TC    32      // t per chunk (NC*TC == S_LEN)

typedef float f4 __attribute__((ext_vector_type(4)));
typedef float f2 __attribute__((ext_vector_type(2)));

// ws layout (floats):
//   xT  : [512][256]            at 0        (131072)
//   acT : f2[512][256]          at 131072   (262144)
//   hp  : f4[NC][512][128]      at 393216   (2097152)   carries, then h_in (in place)
//   P   : [NC][512]             at 2490368  (4096)
// total 2494464 floats ~= 10 MB

__global__ __launch_bounds__(256) void k_transpose_x(const float* __restrict__ x,
                                                     float* __restrict__ xT) {
    __shared__ float tile[32][33];
    const int k0 = blockIdx.x * 32;
    const int t0 = blockIdx.y * 32;
    const int lx = threadIdx.x & 31;
    const int ly = threadIdx.x >> 5;
#pragma unroll
    for (int i = 0; i < 32; i += 8)
        tile[ly + i][lx] = x[(t0 + ly + i) * DM + k0 + lx];
    __syncthreads();
#pragma unroll
    for (int i = 0; i < 32; i += 8)
        xT[(k0 + ly + i) * S_LEN + t0 + lx] = tile[lx][ly + i];
}

// grid(128): block g -> GEMM rows {4g..4g+3, 512+4g..512+4g+3}; epilogue writes acT.
__global__ __launch_bounds__(256) void k_gemm_act(const float* __restrict__ xT,
                                                  const float* __restrict__ W1,
                                                  const float* __restrict__ b1,
                                                  const float* __restrict__ Lam,
                                                  f2* __restrict__ acT) {
    const int g  = blockIdx.x;       // 0..127
    const int t  = threadIdx.x;      // lane axis = t (coalesced xT loads)
    const int r0 = 4 * g;

    float ai[4] = {0.f, 0.f, 0.f, 0.f};
    float ar[4] = {0.f, 0.f, 0.f, 0.f};
    const float* __restrict__ xb = xT + t;

#pragma unroll 8
    for (int k = 0; k < DM; ++k) {
        const float xv = xb[k * S_LEN];
#pragma unroll
        for (int j = 0; j < 4; ++j) {
            ai[j] = fmaf(xv, W1[(r0 + j) * DM + k], ai[j]);        // wave-uniform
            ar[j] = fmaf(xv, W1[(512 + r0 + j) * DM + k], ar[j]);
        }
    }

#pragma unroll
    for (int j = 0; j < 4; ++j) {
        const float pre_i = ai[j] + b1[r0 + j];
        const float pre_r = ar[j] + b1[512 + r0 + j];
        const float inp = 1.f / (1.f + expf(-pre_i));
        const float rec = 1.f / (1.f + expf(-pre_r));
        const float sp  = log1pf(expf(Lam[r0 + j]));
        const float a   = expf(-8.f * sp * rec);
        const float c   = sqrtf(fmaxf(1.f - a * a, 0.f)) * inp;
        f2 ac; ac.x = a; ac.y = c;
        acT[(r0 + j) * S_LEN + t] = ac;
    }
}

// grid(NC*256): block = (chunk c, s-pair g). Computes chunk carry (h from 0) and
// gate product P. No y stores.
__global__ __launch_bounds__(256) void k_carry(const float* __restrict__ x,
                                               const f2* __restrict__ acT,
                                               f4* __restrict__ hp,
                                               float* __restrict__ P) {
    const int c    = blockIdx.x >> 8;
    const int g    = blockIdx.x & 255;
    const int tid  = threadIdx.x;
    const int half = tid >> 7;
    const int s    = 2 * g + half;
    const int dq   = tid & 127;

    __shared__ f2 ac_l[2][TC];
    if (tid < 64) {
        const int h2 = tid >> 5, tt = tid & 31;
        ac_l[h2][tt] = acT[(2 * g + h2) * S_LEN + c * TC + tt];
    }
    __syncthreads();

    const f4* __restrict__ x4 = reinterpret_cast<const f4*>(x);
    f4 h = (f4)0.f;
    float p = 1.f;

#pragma unroll
    for (int t = 0; t < TC; ++t) {
        const f4 xv = x4[(c * TC + t) * 128 + dq];
        const f2 ac = ac_l[half][t];
        const float at = ac.x, ct = ac.y;
        h.x = fmaf(at, h.x, ct * xv.x);
        h.y = fmaf(at, h.y, ct * xv.y);
        h.z = fmaf(at, h.z, ct * xv.z);
        h.w = fmaf(at, h.w, ct * xv.w);
        p *= at;
    }

    hp[(c * DR + s) * 128 + dq] = h;
    if (dq == 0) P[c * DR + s] = p;
}

// grid(256): serial combine over chunks. Overwrites hp[c] with h_in[c] (chunk-entry
// state). Also writes the final state output.
__global__ __launch_bounds__(256) void k_combine(const float* __restrict__ state0,
                                                 f4* __restrict__ hp,
                                                 const float* __restrict__ P,
                                                 f4* __restrict__ out4) {
    const int gg = blockIdx.x * 256 + threadIdx.x;
    const int s  = gg >> 7;
    const int dq = gg & 127;

    const f4* __restrict__ st4 = reinterpret_cast<const f4*>(state0);
    f4 h = st4[s * 128 + dq];

#pragma unroll
    for (int c = 0; c < NC; ++c) {
        const f4 carry = hp[(c * DR + s) * 128 + dq];
        hp[(c * DR + s) * 128 + dq] = h;          // h_in for chunk c
        const float pc = P[c * DR + s];           // wave-uniform
        h.x = fmaf(pc, h.x, carry.x);
        h.y = fmaf(pc, h.y, carry.y);
        h.z = fmaf(pc, h.z, carry.z);
        h.w = fmaf(pc, h.w, carry.w);
    }
    // h is now the final state
    out4[(S_LEN * DR) * 128 + s * 128 + dq] = h;
}

// grid(NC*256): block = (chunk c, s-pair g). Prefetches all TC x rows into
// registers, then a pure fma + nontemporal-store burst.
__global__ __launch_bounds__(256) void k_rec_y(const float* __restrict__ x,
                                               const f4* __restrict__ hin,
                                               const f2* __restrict__ acT,
                                               f4* __restrict__ out4) {
    const int c    = blockIdx.x >> 8;
    const int g    = blockIdx.x & 255;
    const int tid  = threadIdx.x;
    const int half = tid >> 7;
    const int s    = 2 * g + half;
    const int dq   = tid & 127;

    __shared__ f2 ac_l[2][TC];
    if (tid < 64) {
        const int h2 = tid >> 5, tt = tid & 31;
        ac_l[h2][tt] = acT[(2 * g + h2) * S_LEN + c * TC + tt];
    }

    const f4* __restrict__ x4 = reinterpret_cast<const f4*>(x);
    f4 h = hin[(c * DR + s) * 128 + dq];

    f4 xbuf[TC];
#pragma unroll
    for (int t = 0; t < TC; ++t)
        xbuf[t] = x4[(c * TC + t) * 128 + dq];    // 32 independent loads, clustered

    __syncthreads();

#pragma unroll
    for (int t = 0; t < TC; ++t) {
        const f2 ac = ac_l[half][t];
        const float at = ac.x, ct = ac.y;
        h.x = fmaf(at, h.x, ct * xbuf[t].x);
        h.y = fmaf(at, h.y, ct * xbuf[t].y);
        h.z = fmaf(at, h.z, ct * xbuf[t].z);
        h.w = fmaf(at, h.w, ct * xbuf[t].w);
        __builtin_nontemporal_store(h, &out4[((c * TC + t) * DR + s) * 128 + dq]);
    }
}

extern "C" void kernel_launch(void* const* d_in, const int* in_sizes, int n_in,
                              void* d_out, int out_size, void* d_ws, size_t ws_size,
                              hipStream_t stream) {
    const float* x      = (const float*)d_in[0];
    const float* state0 = (const float*)d_in[1];
    const float* W1     = (const float*)d_in[2];
    const float* b1     = (const float*)d_in[3];
    const float* Lam    = (const float*)d_in[4];

    float* ws  = (float*)d_ws;
    float* xT  = ws;                          // 131072 floats
    f2*    acT = (f2*)(ws + 131072);          // 131072 f2
    f4*    hp  = (f4*)(ws + 393216);          // NC*512*128 f4
    float* P   = ws + 2490368;                // NC*512 floats

    f4* out4 = (f4*)d_out;

    k_transpose_x<<<dim3(16, 8), 256, 0, stream>>>(x, xT);
    k_gemm_act<<<dim3(128), 256, 0, stream>>>(xT, W1, b1, Lam, acT);
    k_carry<<<dim3(NC * 256), 256, 0, stream>>>(x, acT, hp, P);
    k_combine<<<dim3(256), 256, 0, stream>>>(state0, hp, P, out4);
    k_rec_y<<<dim3(NC * 256), 256, 0, stream>>>(x, hp, acT, out4);
}